// Round 1
// baseline (271.617 us; speedup 1.0000x reference)
//
#include <hip/hip_runtime.h>

#define BATCH 4
#define SEQ   2048
#define EMB   128
#define NH    16
#define DK    8

// log2(e) / sqrt(8): fold softmax temperature into exp2
#define QSCALE 0.510069726f

// ---------------------------------------------------------------------------
// Kernel 1: fused quantum features + self-attention (q == k == v).
// grid = 64 (b*h) * 4 q-chunks, block = 256 threads, 2 query rows per thread.
// The entire K/V feature matrix for one (b,h) is 2048*8 fp32 = 64 KB -> LDS.
// Features: f[s][d] = prod_{i<=d} cos(x[b,s,h*8+i] + theta[i]), |f| <= 1,
// so |score| <= 8/sqrt(8) and plain exp (no running max) is exact softmax.
// ---------------------------------------------------------------------------
__launch_bounds__(256, 1)
__global__ void qattn_kernel(const float* __restrict__ x,
                             const float* __restrict__ theta,
                             float* __restrict__ att_out /* [B*S, 128] */) {
  __shared__ float4 Kl[SEQ * 2];  // Kl[2*s] = f0..3, Kl[2*s+1] = f4..7

  const int tid    = threadIdx.x;
  const int bh     = blockIdx.x >> 2;
  const int qchunk = blockIdx.x & 3;
  const int b      = bh >> 4;
  const int h      = bh & 15;

  float th[DK];
#pragma unroll
  for (int i = 0; i < DK; ++i) th[i] = theta[i];

  // ---- stage features for all 2048 keys of this (b,h) ----
  const float* xbase = x + (size_t)b * SEQ * EMB + h * DK;
#pragma unroll
  for (int i = 0; i < SEQ / 256; ++i) {
    const int s = i * 256 + tid;
    const float4* xp = (const float4*)(xbase + (size_t)s * EMB);
    const float4 xa = xp[0];
    const float4 xb = xp[1];
    float f0 = __cosf(xa.x + th[0]);
    float f1 = f0 * __cosf(xa.y + th[1]);
    float f2 = f1 * __cosf(xa.z + th[2]);
    float f3 = f2 * __cosf(xa.w + th[3]);
    float f4 = f3 * __cosf(xb.x + th[4]);
    float f5 = f4 * __cosf(xb.y + th[5]);
    float f6 = f5 * __cosf(xb.z + th[6]);
    float f7 = f6 * __cosf(xb.w + th[7]);
    Kl[2 * s]     = make_float4(f0, f1, f2, f3);
    Kl[2 * s + 1] = make_float4(f4, f5, f6, f7);
  }
  __syncthreads();

  // ---- each thread owns 2 query rows ----
  const int r0 = qchunk * 512 + tid;  // and r0 + 256
  float q[2][DK];
#pragma unroll
  for (int r = 0; r < 2; ++r) {
    const int row = r0 + r * 256;
    const float4 a = Kl[2 * row];
    const float4 bq = Kl[2 * row + 1];
    q[r][0] = a.x;  q[r][1] = a.y;  q[r][2] = a.z;  q[r][3] = a.w;
    q[r][4] = bq.x; q[r][5] = bq.y; q[r][6] = bq.z; q[r][7] = bq.w;
  }

  float acc[2][DK];
  float den[2];
#pragma unroll
  for (int r = 0; r < 2; ++r) {
    den[r] = 0.0f;
#pragma unroll
    for (int i = 0; i < DK; ++i) acc[r][i] = 0.0f;
  }

#pragma unroll 4
  for (int j = 0; j < SEQ; ++j) {
    const float4 ka = Kl[2 * j];
    const float4 kb = Kl[2 * j + 1];
#pragma unroll
    for (int r = 0; r < 2; ++r) {
      float d = q[r][0] * ka.x + q[r][1] * ka.y + q[r][2] * ka.z + q[r][3] * ka.w
              + q[r][4] * kb.x + q[r][5] * kb.y + q[r][6] * kb.z + q[r][7] * kb.w;
      const float w = exp2f(d * QSCALE);
      den[r] += w;
      acc[r][0] += w * ka.x; acc[r][1] += w * ka.y;
      acc[r][2] += w * ka.z; acc[r][3] += w * ka.w;
      acc[r][4] += w * kb.x; acc[r][5] += w * kb.y;
      acc[r][6] += w * kb.z; acc[r][7] += w * kb.w;
    }
  }

  // ---- epilogue: normalize, scatter back to [b, s, h*8 + d] layout ----
#pragma unroll
  for (int r = 0; r < 2; ++r) {
    const int s = r0 + r * 256;
    const float inv = 1.0f / den[r];
    float* op = att_out + ((size_t)b * SEQ + s) * EMB + h * DK;
    ((float4*)op)[0] = make_float4(acc[r][0] * inv, acc[r][1] * inv,
                                   acc[r][2] * inv, acc[r][3] * inv);
    ((float4*)op)[1] = make_float4(acc[r][4] * inv, acc[r][5] * inv,
                                   acc[r][6] * inv, acc[r][7] * inv);
  }
}

// ---------------------------------------------------------------------------
// Kernel 2: output projection  out[r,c] = sum_e A[r,e] * W[c,e]
// A: [16384,128], W: [128,128] (w_out, row-major), out: [16384,128].
// 64x64 block tile, 4x4 per-thread register tile, K staged in chunks of 32.
// ---------------------------------------------------------------------------
#define PBM 64
#define PBN 64
#define PBK 32
#define PPITCH 68  // padded pitch (multiple of 4 for b128-aligned reads)

__launch_bounds__(256, 2)
__global__ void proj_kernel(const float* __restrict__ A,
                            const float* __restrict__ W,
                            float* __restrict__ out) {
  __shared__ float As[PBK][PPITCH];
  __shared__ float Ws[PBK][PPITCH];

  const int tid = threadIdx.x;
  const int tx = tid & 15;   // col group
  const int ty = tid >> 4;   // row group
  const int rowbase = blockIdx.x * PBM;
  const int colbase = blockIdx.y * PBN;

  float acc[4][4] = {{0.f}};

  for (int e0 = 0; e0 < EMB; e0 += PBK) {
    // stage A^T tile: As[e][m] = A[rowbase+m][e0+e]
    for (int idx = tid; idx < PBM * PBK / 4; idx += 256) {
      const int m = idx >> 3;
      const int e4 = idx & 7;
      const float4 v = *(const float4*)(A + (size_t)(rowbase + m) * EMB + e0 + e4 * 4);
      As[e4 * 4 + 0][m] = v.x;
      As[e4 * 4 + 1][m] = v.y;
      As[e4 * 4 + 2][m] = v.z;
      As[e4 * 4 + 3][m] = v.w;
    }
    // stage W^T tile: Ws[e][n] = W[colbase+n][e0+e]
    for (int idx = tid; idx < PBN * PBK / 4; idx += 256) {
      const int n = idx >> 3;
      const int e4 = idx & 7;
      const float4 v = *(const float4*)(W + (size_t)(colbase + n) * EMB + e0 + e4 * 4);
      Ws[e4 * 4 + 0][n] = v.x;
      Ws[e4 * 4 + 1][n] = v.y;
      Ws[e4 * 4 + 2][n] = v.z;
      Ws[e4 * 4 + 3][n] = v.w;
    }
    __syncthreads();

#pragma unroll
    for (int e = 0; e < PBK; ++e) {
      const float4 av = *(const float4*)&As[e][ty * 4];
      const float4 wv = *(const float4*)&Ws[e][tx * 4];
      const float a[4] = {av.x, av.y, av.z, av.w};
      const float w[4] = {wv.x, wv.y, wv.z, wv.w};
#pragma unroll
      for (int i = 0; i < 4; ++i)
#pragma unroll
        for (int j = 0; j < 4; ++j) acc[i][j] += a[i] * w[j];
    }
    __syncthreads();
  }

#pragma unroll
  for (int i = 0; i < 4; ++i) {
    float4 o = make_float4(acc[i][0], acc[i][1], acc[i][2], acc[i][3]);
    *(float4*)(out + (size_t)(rowbase + ty * 4 + i) * EMB + colbase + tx * 4) = o;
  }
}

// ---------------------------------------------------------------------------
extern "C" void kernel_launch(void* const* d_in, const int* in_sizes, int n_in,
                              void* d_out, int out_size, void* d_ws, size_t ws_size,
                              hipStream_t stream) {
  const float* x     = (const float*)d_in[0];  // [4,2048,128]
  const float* theta = (const float*)d_in[1];  // [8]
  const float* w_out = (const float*)d_in[2];  // [128,128]
  float* out = (float*)d_out;                  // [4,2048,128]
  float* att = (float*)d_ws;                   // [16384,128] scratch (8 MB)

  // fused features + attention: 64 (b,h) pairs x 4 query chunks
  qattn_kernel<<<dim3(BATCH * NH * 4), dim3(256), 0, stream>>>(x, theta, att);

  // projection: 16384/64 = 256 row tiles, 128/64 = 2 col tiles
  proj_kernel<<<dim3((BATCH * SEQ) / PBM, EMB / PBN), dim3(256), 0, stream>>>(att, w_out, out);
}